// Round 9
// baseline (187.856 us; speedup 1.0000x reference)
//
#include <hip/hip_runtime.h>
#include <stdint.h>

// Problem constants (from reference): B=4, N=8192, D=512, H=8, Dh=64
#define SEQ      8192
#define BATCH    4
#define DIM      512
#define MROWS    32768      // BATCH*SEQ
#define CHUNK    64
#define NCHUNK   128        // SEQ / CHUNK (per batch); 512 global chunks
#define NCHAN    2048       // BATCH * DIM
#define NGCHUNK  512        // BATCH * NCHUNK
#define XLD      136        // X tile row stride (128 + 8 pad)
#define NITER    16         // DIM / 32 K-steps

typedef unsigned short ushort;
typedef unsigned int   uint;
typedef __bf16 bf16x8 __attribute__((ext_vector_type(8)));
typedef float  f32x4  __attribute__((ext_vector_type(4)));
typedef ushort usx8   __attribute__((ext_vector_type(8)));

// native RNE f32->bf16 (hardware cvt)
__device__ __forceinline__ ushort f2bf(float f) {
    union { __bf16 h; ushort u; } cv;
    cv.h = (__bf16)f;
    return cv.u;
}
__device__ __forceinline__ float bf2f(ushort v) {
    return __uint_as_float(((unsigned)v) << 16);
}

// both weight matrices in one launch; outputs contiguous (win_bf then wout_bf)
__global__ void weights_to_bf16_kernel(const float* __restrict__ w_in,
                                       const float* __restrict__ w_out,
                                       ushort* __restrict__ dst, int n4each) {
    int i = blockIdx.x * blockDim.x + threadIdx.x;
    if (i >= 2 * n4each) return;
    const float4* src = (i < n4each) ? (const float4*)w_in
                                     : (const float4*)w_out - n4each;
    float4 v = src[i];
    ushort4 r;
    r.x = f2bf(v.x); r.y = f2bf(v.y); r.z = f2bf(v.z); r.w = f2bf(v.w);
    ((ushort4*)dst)[i] = r;
}

#define GLDS(g, l) __builtin_amdgcn_global_load_lds(                        \
        (const __attribute__((address_space(1))) void*)(g),                 \
        (__attribute__((address_space(3))) void*)(l), 16, 0, 0)

#define WAITV(n)  asm volatile("s_waitcnt vmcnt(" #n ")" ::: "memory")
#define WAITL0()  asm volatile("s_waitcnt lgkmcnt(0)" ::: "memory")
#define BAR()     do { __builtin_amdgcn_s_barrier();                        \
                       __builtin_amdgcn_sched_barrier(0); } while (0)
#define SBAR()    __builtin_amdgcn_sched_barrier(0)

// XCD-aware tile remap: 1024 blocks, 8 XCDs, 128 blocks/XCD; the 4 bn
// siblings of one bm (sharing A rows) become consecutive on ONE XCD's L2.
__device__ __forceinline__ void tile_decode(int& bm, int& bn) {
    const int orig = blockIdx.y * gridDim.x + blockIdx.x;   // dispatch-linear
    const int tl   = (orig & 7) * 128 + (orig >> 3);        // bijective (1024%8==0)
    bm = tl >> 2; bn = tl & 3;
}

// LDS XOR swizzle (verified round 8: conflicts 2.36M -> 0.26M): within each
// 64-B row of 4x16-B slots, content slot q lives at physical q ^ ((row>>1)&3).
// B: pre-swizzled global source (GLDS dest linear). A: swizzled ds_write addr.
// Readers use quad ^ ((r16>>1)&3).

// =====================================================================
// GEMM1 + fused chunk-local scan. 128x128 tile, 256 thr (4 waves 2x2 of
// 64x64), 2-buffer staging, counted vmcnt, all staging post-BAR.
//   xp = x @ W_in^T + b_in (tile kept in LDS); z_loc' scan in epilogue;
//   writes z_loc' (bf16), L' (f32), XpT (f32). Carry applied in GEMM2.
// A (x fp32) reg-staged 2 sets (load k+2 at iter k, ds_write k+1); B via
// GLDS. Race audit: stage targets buf read at k-1, issued post-BAR(k);
// GLDS(k+1) retired by WAITV(4) pre-BAR(k+1); ds_write drained by WAITL0.
// =====================================================================
__global__ __launch_bounds__(256, 4) void gemm1_scan_kernel(
        const float* __restrict__ x,    const ushort* __restrict__ Bw,
        const float* __restrict__ b_in, const float* __restrict__ alpha_param,
        ushort* __restrict__ zout,
        float* __restrict__ Lfin,       float* __restrict__ XpT)
{
    // LDS: 2x(8KB As + 8KB Bs) = 32 KB, overlaid with X[128][136] (34 KB)
    __shared__ __align__(16) char smem[34816];
    ushort* As0 = (ushort*)smem;                 // 2 bufs x 4096 ushorts
    ushort* Bs0 = (ushort*)(smem + 16384);       // 2 bufs x 4096 ushorts
    ushort* X   = (ushort*)smem;                 // [128][XLD] (epilogue)

    const int tid = threadIdx.x;            // 0..255
    int bm, bn; tile_decode(bm, bn);        // bm 0..255, bn 0..3

    const int lane = tid & 63;
    const int wave = tid >> 6;              // 0..3
    const int wr = wave >> 1, wc = wave & 1;
    const int quad = lane >> 4, r16 = lane & 15;

    // B staging (GLDS): thread -> row = tid>>2 (0..63) and +64, slot = tid&3
    const int brow = tid >> 2;
    const int bslot = tid & 3;
    const int brx = (brow >> 1) & 3;        // same for row+64
    const ushort* Bg0 = Bw + (size_t)(bn * 128 + brow) * DIM + ((bslot ^ brx) << 3);
    const ushort* Bg1 = Bg0 + (size_t)64 * DIM;

    // A staging: thread -> row = tid>>1 (0..127), 16 cols at skoff
    const int srow  = tid >> 1;
    const int skoff = (tid & 1) * 16;
    const int arx   = (srow >> 1) & 3;
    const float* Ag = x + (size_t)(bm * 128 + srow) * DIM + skoff;
    const int aw0 = srow * 32 + (((2 * (tid & 1) + 0) ^ arx) << 3);
    const int aw1 = srow * 32 + (((2 * (tid & 1) + 1) ^ arx) << 3);

    f32x4 acc[4][4];
    #pragma unroll
    for (int i = 0; i < 4; i++)
        #pragma unroll
        for (int j = 0; j < 4; j++)
            acc[i][j] = f32x4{0.f, 0.f, 0.f, 0.f};

    auto stageB = [&](int k0, int b) {
        GLDS(Bg0 + k0, &Bs0[b * 4096 + tid * 8]);
        GLDS(Bg1 + k0, &Bs0[b * 4096 + 2048 + tid * 8]);
    };
    auto cvt8 = [&](float4 lo, float4 hi) {
        usx8 w;
        w[0] = f2bf(lo.x); w[1] = f2bf(lo.y); w[2] = f2bf(lo.z); w[3] = f2bf(lo.w);
        w[4] = f2bf(hi.x); w[5] = f2bf(hi.y); w[6] = f2bf(hi.z); w[7] = f2bf(hi.w);
        return w;
    };

    // A reg sets: data(j) lives in set (j&1). 4 float4 per set.
    float4 a00, a01, a02, a03, a10, a11, a12, a13;

    // prologue: stage buf0 (B) + load A(0),A(1); write As[0]
    stageB(0, 0);
    a00 = *(const float4*)(Ag);      a01 = *(const float4*)(Ag + 4);
    a02 = *(const float4*)(Ag + 8);  a03 = *(const float4*)(Ag + 12);
    a10 = *(const float4*)(Ag + 32); a11 = *(const float4*)(Ag + 36);
    a12 = *(const float4*)(Ag + 40); a13 = *(const float4*)(Ag + 44);
    *(usx8*)&As0[aw0] = cvt8(a00, a01);   // auto vmcnt(4): retires B(0)+A(0)
    *(usx8*)&As0[aw1] = cvt8(a02, a03);
    WAITV(4); WAITL0(); BAR();

    const int rxr = (r16 >> 1) & 3;

    #pragma unroll
    for (int k = 0; k < NITER; ++k) {
        const int cb = k & 1, nb = cb ^ 1;

        // post-BAR staging: GLDS B(k+1); A-loads(k+2); ds_write A(k+1)
        if (k + 1 < NITER) stageB((k + 1) * 32, nb);
        if (k + 2 < NITER) {
            const int ko = (k + 2) * 32;
            if ((k & 1) == 0) {
                a00 = *(const float4*)(Ag + ko);      a01 = *(const float4*)(Ag + ko + 4);
                a02 = *(const float4*)(Ag + ko + 8);  a03 = *(const float4*)(Ag + ko + 12);
            } else {
                a10 = *(const float4*)(Ag + ko);      a11 = *(const float4*)(Ag + ko + 4);
                a12 = *(const float4*)(Ag + ko + 8);  a13 = *(const float4*)(Ag + ko + 12);
            }
        }
        if (k + 1 < NITER) {   // data(k+1) in set ((k+1)&1), loaded at k-1
            if ((k & 1) == 0) {
                *(usx8*)&As0[nb * 4096 + aw0] = cvt8(a10, a11);
                *(usx8*)&As0[nb * 4096 + aw1] = cvt8(a12, a13);
            } else {
                *(usx8*)&As0[nb * 4096 + aw0] = cvt8(a00, a01);
                *(usx8*)&As0[nb * 4096 + aw1] = cvt8(a02, a03);
            }
        }

        bf16x8 af[4], bfr[4];
        #pragma unroll
        for (int i = 0; i < 4; i++)
            af[i] = *(const bf16x8*)&As0[cb * 4096 + (wr * 64 + i * 16 + r16) * 32
                                         + ((quad ^ rxr) << 3)];
        #pragma unroll
        for (int j = 0; j < 4; j++)
            bfr[j] = *(const bf16x8*)&Bs0[cb * 4096 + (wc * 64 + j * 16 + r16) * 32
                                          + ((quad ^ rxr) << 3)];
        WAITL0();
        SBAR();
        __builtin_amdgcn_s_setprio(1);
        #pragma unroll
        for (int i = 0; i < 4; i++)
            #pragma unroll
            for (int j = 0; j < 4; j++)
                acc[i][j] = __builtin_amdgcn_mfma_f32_16x16x32_bf16(
                                bfr[j], af[i], acc[i][j], 0, 0, 0);  // swapped
        __builtin_amdgcn_s_setprio(0);

        if (k < NITER - 2) WAITV(4); else WAITV(0);   // retire GLDS(k+1)
        BAR();
    }

    // ---- epilogue part 1: xp tile (C + bias) -> LDS X[128][XLD] (bf16)
    __syncthreads();
    #pragma unroll
    for (int i = 0; i < 4; i++) {
        const int ml = wr * 64 + i * 16 + r16;
        #pragma unroll
        for (int j = 0; j < 4; j++) {
            const int nl = wc * 64 + j * 16 + quad * 4;
            const float4 bv = *(const float4*)&b_in[bn * 128 + nl];
            ushort4 r4;
            r4.x = f2bf(acc[i][j][0] + bv.x);
            r4.y = f2bf(acc[i][j][1] + bv.y);
            r4.z = f2bf(acc[i][j][2] + bv.z);
            r4.w = f2bf(acc[i][j][3] + bv.w);
            *(ushort4*)&X[ml * XLD + nl] = r4;
        }
    }
    __syncthreads();

    // ---- epilogue part 2: chunk-local scan (prev = 0 at chunk start)
    // 256 threads = 2 chunks x 128 channels
    const int chalf = tid >> 7;             // 0..1
    const int cidx  = tid & 127;            // 0..127
    const int g     = 2 * bm + chalf;       // global chunk 0..511
    const int d     = bn * 128 + cidx;      // 0..511
    const int h     = d >> 6;
    const float alpha = 1.0f / (1.0f + expf(-alpha_param[h]));
    const float c     = 1.0f - alpha;

    const ushort* Xr  = X + chalf * 64 * XLD + cidx;
    ushort* zrow = zout + ((size_t)(bm * 128 + chalf * 64)) * DIM + d;

    float z = 0.f, prev = 0.f;
    #pragma unroll 8
    for (int r = 0; r < CHUNK; ++r) {
        float xv = bf2f(Xr[r * XLD]);
        z = c * z + alpha * (xv - prev);
        prev = xv;
        zrow[(size_t)r * DIM] = f2bf(z);
    }
    Lfin[(size_t)g * 512 + d]       = z;     // L' tail
    XpT[(size_t)(g + 1) * 512 + d]  = prev;  // xp tail -> next chunk's xpt
}

// =====================================================================
// Carry chain:  G_k = c*Z_k - alpha*xpt_k ;  Z_{k+1} = L'_k + c^63 * G_k
// =====================================================================
__global__ void scan_fixg_kernel(const float* __restrict__ Lfin,
                                 const float* __restrict__ XpT,
                                 const float* __restrict__ alpha_param,
                                 const float* __restrict__ init_state,
                                 float* __restrict__ G)
{
    int ch = blockIdx.x * blockDim.x + threadIdx.x;   // 0..2047
    if (ch >= NCHAN) return;
    const int b = ch >> 9;
    const int d = ch & (DIM - 1);
    const int h = d >> 6;
    const float alpha = 1.0f / (1.0f + expf(-alpha_param[h]));
    const float c = 1.0f - alpha;
    const float c2 = c * c, c4 = c2 * c2, c8 = c4 * c4,
                c16 = c8 * c8, c32 = c16 * c16;
    const float c63 = c32 * c16 * c8 * c4 * c2 * c;
    const float sinit = init_state[d];

    float Z = sinit;
    const float* Lp = Lfin + (size_t)(b * NCHUNK) * 512 + d;
    const float* Xp = XpT  + (size_t)(b * NCHUNK) * 512 + d;
    float*       Gp = G    + (size_t)(b * NCHUNK) * 512 + d;

    constexpr int PF = 16;
    float Lr[PF], Xr[PF];
    #pragma unroll
    for (int j = 0; j < PF; ++j) {
        Lr[j] = Lp[(size_t)j * 512];
        Xr[j] = Xp[(size_t)j * 512];
    }
    for (int gr = 0; gr < NCHUNK / PF; ++gr) {        // 8 groups
        #pragma unroll
        for (int j = 0; j < PF; ++j) {
            const int kl = gr * PF + j;
            const float xpt = (kl == 0) ? sinit : Xr[j];
            const float Lc  = Lr[j];
            if (gr + 1 < NCHUNK / PF) {
                Lr[j] = Lp[(size_t)((gr + 1) * PF + j) * 512];
                Xr[j] = Xp[(size_t)((gr + 1) * PF + j) * 512];
            }
            const float Gv = c * Z - alpha * xpt;
            Gp[(size_t)kl * 512] = Gv;
            Z = Lc + c63 * Gv;
        }
    }
}

// =====================================================================
// GEMM2: out = z @ W_out^T + b_out ; carry correction fused in A-staging:
//   a[tau, d] += c_h^tau * G[g][d]   (g = row>>6, tau = row&63)
// Same 128^2/4-wave/2-buffer schedule. The block's 2 G rows (1 KB each)
// are GLDS'd ONCE into LDS in the prologue; per-iter G reads are
// broadcast ds_reads (2 distinct addrs/wave) -- saves 16 VGPR vs regs.
// =====================================================================
__global__ __launch_bounds__(256, 4) void gemm2_kernel(
        const ushort* __restrict__ Az, const ushort* __restrict__ Bw,
        const float* __restrict__ bias, float* __restrict__ Cout,
        const float* __restrict__ G, const float* __restrict__ alpha_param)
{
    __shared__ __align__(16) char smem[36864];   // 32 KB staging + 4 KB G
    ushort* As0 = (ushort*)smem;                 // 2 bufs x 4096 ushorts
    ushort* Bs0 = (ushort*)(smem + 16384);       // 2 bufs x 4096 ushorts
    float*  Gl  = (float*)(smem + 32768);        // [2][512] floats

    const int tid = threadIdx.x;
    int bm, bn; tile_decode(bm, bn);

    const int lane = tid & 63;
    const int wave = tid >> 6;
    const int wr = wave >> 1, wc = wave & 1;
    const int quad = lane >> 4, r16 = lane & 15;

    const int brow = tid >> 2;
    const int bslot = tid & 3;
    const int brx = (brow >> 1) & 3;
    const ushort* Bg0 = Bw + (size_t)(bn * 128 + brow) * DIM + ((bslot ^ brx) << 3);
    const ushort* Bg1 = Bg0 + (size_t)64 * DIM;

    const int srow  = tid >> 1;
    const int skoff = (tid & 1) * 16;
    const int arx   = (srow >> 1) & 3;
    const ushort* Ag16 = Az + (size_t)(bm * 128 + srow) * DIM + skoff;
    const int aw0 = srow * 32 + (((2 * (tid & 1) + 0) ^ arx) << 3);
    const int aw1 = srow * 32 + (((2 * (tid & 1) + 1) ^ arx) << 3);
    const int grow = srow >> 6;             // 0..1: which G row

    // c_h^tau factors (tau = srow & 63) as named scalars + select chain
    const float t1 = (float)(srow & 63);
    float fc0,fc1,fc2,fc3,fc4,fc5,fc6,fc7;
    {
        float a, c;
        a = 1.f/(1.f+expf(-alpha_param[0])); c = 1.f - a; fc0 = exp2f(t1 * log2f(c));
        a = 1.f/(1.f+expf(-alpha_param[1])); c = 1.f - a; fc1 = exp2f(t1 * log2f(c));
        a = 1.f/(1.f+expf(-alpha_param[2])); c = 1.f - a; fc2 = exp2f(t1 * log2f(c));
        a = 1.f/(1.f+expf(-alpha_param[3])); c = 1.f - a; fc3 = exp2f(t1 * log2f(c));
        a = 1.f/(1.f+expf(-alpha_param[4])); c = 1.f - a; fc4 = exp2f(t1 * log2f(c));
        a = 1.f/(1.f+expf(-alpha_param[5])); c = 1.f - a; fc5 = exp2f(t1 * log2f(c));
        a = 1.f/(1.f+expf(-alpha_param[6])); c = 1.f - a; fc6 = exp2f(t1 * log2f(c));
        a = 1.f/(1.f+expf(-alpha_param[7])); c = 1.f - a; fc7 = exp2f(t1 * log2f(c));
    }
    auto selfac = [&](int hh) -> float {
        float f = fc0;
        f = (hh == 1) ? fc1 : f;
        f = (hh == 2) ? fc2 : f;
        f = (hh == 3) ? fc3 : f;
        f = (hh == 4) ? fc4 : f;
        f = (hh == 5) ? fc5 : f;
        f = (hh == 6) ? fc6 : f;
        f = (hh == 7) ? fc7 : f;
        return f;
    };

    f32x4 acc[4][4];
    #pragma unroll
    for (int i = 0; i < 4; i++)
        #pragma unroll
        for (int j = 0; j < 4; j++)
            acc[i][j] = f32x4{0.f, 0.f, 0.f, 0.f};

    auto stageB = [&](int k0, int b) {
        GLDS(Bg0 + k0, &Bs0[b * 4096 + tid * 8]);
        GLDS(Bg1 + k0, &Bs0[b * 4096 + 2048 + tid * 8]);
    };
    // fixpack: z (2 usx8) + G from LDS at dbase -> 2 swizzled ds_writes
    auto writeFixed = [&](int nb, usx8 z0, usx8 z1, int dbase) {
        const float fac = selfac(dbase >> 6);
        float4 gA = *(const float4*)&Gl[grow * 512 + dbase];
        float4 gB = *(const float4*)&Gl[grow * 512 + dbase + 4];
        float4 gC = *(const float4*)&Gl[grow * 512 + dbase + 8];
        float4 gD = *(const float4*)&Gl[grow * 512 + dbase + 12];
        usx8 w0, w1;
        w0[0] = f2bf(bf2f(z0[0]) + fac * gA.x);
        w0[1] = f2bf(bf2f(z0[1]) + fac * gA.y);
        w0[2] = f2bf(bf2f(z0[2]) + fac * gA.z);
        w0[3] = f2bf(bf2f(z0[3]) + fac * gA.w);
        w0[4] = f2bf(bf2f(z0[4]) + fac * gB.x);
        w0[5] = f2bf(bf2f(z0[5]) + fac * gB.y);
        w0[6] = f2bf(bf2f(z0[6]) + fac * gB.z);
        w0[7] = f2bf(bf2f(z0[7]) + fac * gB.w);
        w1[0] = f2bf(bf2f(z1[0]) + fac * gC.x);
        w1[1] = f2bf(bf2f(z1[1]) + fac * gC.y);
        w1[2] = f2bf(bf2f(z1[2]) + fac * gC.z);
        w1[3] = f2bf(bf2f(z1[3]) + fac * gC.w);
        w1[4] = f2bf(bf2f(z1[4]) + fac * gD.x);
        w1[5] = f2bf(bf2f(z1[5]) + fac * gD.y);
        w1[6] = f2bf(bf2f(z1[6]) + fac * gD.z);
        w1[7] = f2bf(bf2f(z1[7]) + fac * gD.w);
        *(usx8*)&As0[nb * 4096 + aw0] = w0;
        *(usx8*)&As0[nb * 4096 + aw1] = w1;
    };

    // z reg sets: data(j) in set (j&1); 2 usx8 per set
    usx8 z00, z01, z10, z11;

    // prologue: GLDS G rows (1 op), stage B(0), load z(0), z(1)
    GLDS((const float*)G + (size_t)bm * 1024 + tid * 4, (char*)Gl + tid * 16);
    stageB(0, 0);
    z00 = *(const usx8*)(Ag16);      z01 = *(const usx8*)(Ag16 + 8);
    z10 = *(const usx8*)(Ag16 + 32); z11 = *(const usx8*)(Ag16 + 40);
    WAITV(6);                        // retire G-GLDS (6 younger ops)
    writeFixed(0, z00, z01, skoff);  // auto-waits z(0) (vmcnt<=2)
    WAITV(2); WAITL0(); BAR();       // retire B(0); z(1) in flight

    const int rxr = (r16 >> 1) & 3;

    #pragma unroll
    for (int k = 0; k < NITER; ++k) {
        const int cb = k & 1, nb = cb ^ 1;

        if (k + 1 < NITER) stageB((k + 1) * 32, nb);
        if (k + 2 < NITER) {
            const int ko = (k + 2) * 32;
            if ((k & 1) == 0) {
                z00 = *(const usx8*)(Ag16 + ko); z01 = *(const usx8*)(Ag16 + ko + 8);
            } else {
                z10 = *(const usx8*)(Ag16 + ko); z11 = *(const usx8*)(Ag16 + ko + 8);
            }
        }
        if (k + 1 < NITER) {
            const int dbase = (k + 1) * 32 + skoff;
            if ((k & 1) == 0) writeFixed(nb, z10, z11, dbase);
            else              writeFixed(nb, z00, z01, dbase);
        }

        bf16x8 af[4], bfr[4];
        #pragma unroll
        for (int i = 0; i < 4; i++)
            af[i] = *(const bf16x8*)&As0[cb * 4096 + (wr * 64 + i * 16 + r16) * 32
                                         + ((quad ^ rxr) << 3)];
        #pragma unroll
        for (int j = 0; j < 4; j++)
            bfr[j] = *(const bf16x8*)&Bs0[cb * 4096 + (wc * 64 + j * 16 + r16) * 32
                                          + ((quad ^ rxr) << 3)];
        WAITL0();
        SBAR();
        __builtin_amdgcn_s_setprio(1);
        #pragma unroll
        for (int i = 0; i < 4; i++)
            #pragma unroll
            for (int j = 0; j < 4; j++)
                acc[i][j] = __builtin_amdgcn_mfma_f32_16x16x32_bf16(
                                bfr[j], af[i], acc[i][j], 0, 0, 0);  // swapped
        __builtin_amdgcn_s_setprio(0);

        if (k < NITER - 2) WAITV(2); else WAITV(0);   // retire GLDS(k+1)
        BAR();
    }

    // epilogue: m = lane&15 (per i-tile), n = quad*4 + reg
    #pragma unroll
    for (int i = 0; i < 4; i++) {
        const int mr = bm * 128 + wr * 64 + i * 16 + r16;
        #pragma unroll
        for (int j = 0; j < 4; j++) {
            const int n0 = bn * 128 + wc * 64 + j * 16 + quad * 4;
            const float4 bv = *(const float4*)&bias[n0];
            float4 v = make_float4(acc[i][j][0] + bv.x, acc[i][j][1] + bv.y,
                                   acc[i][j][2] + bv.z, acc[i][j][3] + bv.w);
            *(float4*)&Cout[(size_t)mr * DIM + n0] = v;
        }
    }
}

extern "C" void kernel_launch(void* const* d_in, const int* in_sizes, int n_in,
                              void* d_out, int out_size, void* d_ws, size_t ws_size,
                              hipStream_t stream) {
    const float* x           = (const float*)d_in[0];
    const float* W_in        = (const float*)d_in[1];
    const float* b_in        = (const float*)d_in[2];
    const float* W_out       = (const float*)d_in[3];
    const float* b_out       = (const float*)d_in[4];
    const float* init_state  = (const float*)d_in[5];
    const float* alpha_param = (const float*)d_in[6];
    float* out = (float*)d_out;

    // workspace layout
    ushort* z_bf    = (ushort*)d_ws;                       // 32 MB
    ushort* win_bf  = z_bf   + (size_t)MROWS * DIM;        // 0.5 MB
    ushort* wout_bf = win_bf + (size_t)DIM * DIM;          // 0.5 MB
    float*  Lfin    = (float*)(wout_bf + (size_t)DIM * DIM);        // [512][512]
    float*  XpT     = Lfin + (size_t)NGCHUNK * 512;                 // [513][512]
    float*  G       = XpT  + (size_t)(NGCHUNK + 1) * 512;           // [512][512]

    const int nw4 = (DIM * DIM) / 4;          // 65,536
    weights_to_bf16_kernel<<<(2 * nw4 + 255) / 256, 256, 0, stream>>>(
        W_in, W_out, win_bf, nw4);

    dim3 g1(DIM / 128, MROWS / 128);          // (4, 256) = 1024 blocks
    gemm1_scan_kernel<<<g1, 256, 0, stream>>>(
        x, win_bf, b_in, alpha_param, z_bf, Lfin, XpT);

    scan_fixg_kernel<<<NCHAN / 256, 256, 0, stream>>>(
        Lfin, XpT, alpha_param, init_state, G);

    dim3 g2(DIM / 128, MROWS / 128);          // (4, 256)
    gemm2_kernel<<<g2, 256, 0, stream>>>(
        z_bf, wout_bf, b_out, out, G, alpha_param);
}

// Round 10
// 180.656 us; speedup vs baseline: 1.0399x; 1.0399x over previous
//
#include <hip/hip_runtime.h>
#include <stdint.h>

// Problem constants (from reference): B=4, N=8192, D=512, H=8, Dh=64
#define SEQ      8192
#define BATCH    4
#define DIM      512
#define MROWS    32768      // BATCH*SEQ
#define CHUNK    64
#define NCHUNK   128        // SEQ / CHUNK (per batch); 512 global chunks
#define NCHAN    2048       // BATCH * DIM
#define NGCHUNK  512        // BATCH * NCHUNK
#define XLD      264        // X tile row stride (256 + 8 pad)
#define NITER    16         // DIM / 32 K-steps

typedef unsigned short ushort;
typedef unsigned int   uint;
typedef __bf16 bf16x8 __attribute__((ext_vector_type(8)));
typedef float  f32x4  __attribute__((ext_vector_type(4)));
typedef ushort usx8   __attribute__((ext_vector_type(8)));

// native RNE f32->bf16 (hardware cvt)
__device__ __forceinline__ ushort f2bf(float f) {
    union { __bf16 h; ushort u; } cv;
    cv.h = (__bf16)f;
    return cv.u;
}
__device__ __forceinline__ float bf2f(ushort v) {
    return __uint_as_float(((unsigned)v) << 16);
}

// both weight matrices in one launch; outputs contiguous (win_bf then wout_bf)
__global__ void weights_to_bf16_kernel(const float* __restrict__ w_in,
                                       const float* __restrict__ w_out,
                                       ushort* __restrict__ dst, int n4each) {
    int i = blockIdx.x * blockDim.x + threadIdx.x;
    if (i >= 2 * n4each) return;
    const float4* src = (i < n4each) ? (const float4*)w_in
                                     : (const float4*)w_out - n4each;
    float4 v = src[i];
    ushort4 r;
    r.x = f2bf(v.x); r.y = f2bf(v.y); r.z = f2bf(v.z); r.w = f2bf(v.w);
    ((ushort4*)dst)[i] = r;
}

#define GLDS(g, l) __builtin_amdgcn_global_load_lds(                        \
        (const __attribute__((address_space(1))) void*)(g),                 \
        (__attribute__((address_space(3))) void*)(l), 16, 0, 0)

#define WAITV(n)  asm volatile("s_waitcnt vmcnt(" #n ")" ::: "memory")
#define WAITL0()  asm volatile("s_waitcnt lgkmcnt(0)" ::: "memory")
#define BAR()     do { __builtin_amdgcn_s_barrier();                        \
                       __builtin_amdgcn_sched_barrier(0); } while (0)
#define SBAR()    __builtin_amdgcn_sched_barrier(0)

// XCD-aware remap for 512 blocks (8 XCDs x 64): bn-siblings sharing an
// A-row panel become adjacent on ONE XCD's L2 (round 9: FETCH halved).
__device__ __forceinline__ void tile_decode(int& bm, int& bn) {
    const int orig = blockIdx.y * gridDim.x + blockIdx.x;   // 0..511
    const int tl   = (orig & 7) * 64 + (orig >> 3);         // bijective
    bm = tl >> 1; bn = tl & 1;
}

// LDS XOR swizzle (verified round 8: conflicts 2.36M -> 0.26M): within each
// 64-B row of 4x16-B slots, content slot q lives at physical q ^ ((row>>1)&3).

// =====================================================================
// GEMM1 + fused chunk-local scan (round-8 structure, 128x256, 8 waves,
// 3 LDS bufs) + THREE A-register sets: P1(k) loads A(k+3) into set k%3,
// P2(k) ds_writes As[(k+1)%3] from set (k+1)%3 (loaded at P1(k-2)) ->
// A-loads get 2 full iterations of HBM-latency cover (was 1).
// WAITV ladder (GLDS for buf k, issued P1(k-2)): k=0 -> 2 (prologue B0,
// B1 pair outstanding), k=1..13 -> 4, k=14 -> 2, k=15 -> 0.
// =====================================================================
__global__ __launch_bounds__(512, 4) void gemm1_scan_kernel(
        const float* __restrict__ x,    const ushort* __restrict__ Bw,
        const float* __restrict__ b_in, const float* __restrict__ alpha_param,
        ushort* __restrict__ zout,
        float* __restrict__ Lfin,       float* __restrict__ XpT)
{
    // LDS: 3x(8KB As + 16KB Bs) = 72 KB, overlaid with X[128][XLD] (66 KB)
    __shared__ __align__(16) char smem[73728];
    ushort* As0 = (ushort*)smem;                 // 3 bufs x 4096 ushorts
    ushort* Bs0 = (ushort*)(smem + 24576);       // 3 bufs x 8192 ushorts
    ushort* X   = (ushort*)smem;                 // [128][XLD] (epilogue)

    const int tid = threadIdx.x;            // 0..511
    int bm, bn; tile_decode(bm, bn);        // bm 0..255, bn 0..1

    const int lane = tid & 63;
    const int wave = tid >> 6;
    const int wr = wave >> 2, wc = wave & 3;
    const int quad = lane >> 4, r16 = lane & 15;

    // staging map: thread -> row = tid>>2 (0..127), k-slot = tid&3
    const int srow  = tid >> 2;
    const int ks    = tid & 3;
    const int rx    = (srow >> 1) & 3;      // row-XOR (bits 1-2)
    const int skoff = ks * 8;               // A content k-offset
    const float*  Ag  = x  + (size_t)(bm * 128 + srow) * DIM + skoff;
    const ushort* Bg0 = Bw + (size_t)(bn * 256 + srow) * DIM + ((ks ^ rx) << 3);
    const ushort* Bg1 = Bg0 + (size_t)128 * DIM;
    const int aWrOff = srow * 32 + ((ks ^ rx) << 3);

    f32x4 acc[4][4];
    #pragma unroll
    for (int i = 0; i < 4; i++)
        #pragma unroll
        for (int j = 0; j < 4; j++)
            acc[i][j] = f32x4{0.f, 0.f, 0.f, 0.f};

    auto stageB = [&](int k0, int b) {
        GLDS(Bg0 + k0, &Bs0[b * 8192 + tid * 8]);
        GLDS(Bg1 + k0, &Bs0[b * 8192 + 4096 + tid * 8]);
    };
    auto packA = [&](float4 lo, float4 hi) {
        usx8 w;
        w[0] = f2bf(lo.x); w[1] = f2bf(lo.y); w[2] = f2bf(lo.z); w[3] = f2bf(lo.w);
        w[4] = f2bf(hi.x); w[5] = f2bf(hi.y); w[6] = f2bf(hi.z); w[7] = f2bf(hi.w);
        return w;
    };

    // 3 A reg sets: set j holds A(t) with t%3 == j
    float4 aL0, aH0, aL1, aH1, aL2, aH2;

    // prologue: load A(0),A(1),A(2); stage B(0),B(1); write As[0]
    aL0 = *(const float4*)(Ag);      aH0 = *(const float4*)(Ag + 4);
    aL1 = *(const float4*)(Ag + 32); aH1 = *(const float4*)(Ag + 36);
    aL2 = *(const float4*)(Ag + 64); aH2 = *(const float4*)(Ag + 68);
    stageB(0, 0);
    stageB(32, 1);
    *(usx8*)&As0[aWrOff] = packA(aL0, aH0);   // auto vmcnt(8): waits A(0)

    const int rxr = (r16 >> 1) & 3;

    #pragma unroll
    for (int k = 0; k < NITER; ++k) {
        const int cur = k % 3;
        const int stg = (k + 2) % 3;
        const int wnx = (k + 1) % 3;

        // P2: ds_write As[k+1] from set (k+1)%3 (loaded at P1(k-2) -> auto
        // vmcnt(6) = 2 iterations of cover for the A-loads)
        if (k + 1 < NITER) {
            usx8 w;
            if (wnx == 0)      w = packA(aL0, aH0);
            else if (wnx == 1) w = packA(aL1, aH1);
            else               w = packA(aL2, aH2);
            *(usx8*)&As0[wnx * 4096 + aWrOff] = w;
        }
        // GLDS backstop ladder (retire B for buf k) + lgkm + rendezvous
        if (k == 0)       WAITV(2);
        else if (k <= 13) WAITV(4);
        else if (k == 14) WAITV(2);
        else              WAITV(0);
        WAITL0();
        BAR();

        // P1 (POST-BAR): A-loads(k+3) into set k%3 [pinned first], B(k+2)
        if (k + 3 < NITER) {
            const int ko = (k + 3) * 32;
            if (cur == 0)      { aL0 = *(const float4*)(Ag + ko); aH0 = *(const float4*)(Ag + ko + 4); }
            else if (cur == 1) { aL1 = *(const float4*)(Ag + ko); aH1 = *(const float4*)(Ag + ko + 4); }
            else               { aL2 = *(const float4*)(Ag + ko); aH2 = *(const float4*)(Ag + ko + 4); }
        }
        SBAR();
        if (k + 2 < NITER) stageB((k + 2) * 32, stg);

        bf16x8 af[4], bfr[4];
        #pragma unroll
        for (int i = 0; i < 4; i++)
            af[i] = *(const bf16x8*)&As0[cur * 4096 + (wr * 64 + i * 16 + r16) * 32
                                         + ((quad ^ rxr) << 3)];
        #pragma unroll
        for (int j = 0; j < 4; j++)
            bfr[j] = *(const bf16x8*)&Bs0[cur * 8192 + (wc * 64 + j * 16 + r16) * 32
                                          + ((quad ^ rxr) << 3)];

        #pragma unroll
        for (int i = 0; i < 4; i++)
            #pragma unroll
            for (int j = 0; j < 4; j++)
                acc[i][j] = __builtin_amdgcn_mfma_f32_16x16x32_bf16(
                                bfr[j], af[i], acc[i][j], 0, 0, 0);  // swapped
    }

    // ---- epilogue part 1: xp tile (C + bias) -> LDS X[128][XLD] (bf16)
    __syncthreads();   // full drain; all waves done reading As/Bs
    #pragma unroll
    for (int i = 0; i < 4; i++) {
        const int ml = wr * 64 + i * 16 + r16;
        #pragma unroll
        for (int j = 0; j < 4; j++) {
            const int nl = wc * 64 + j * 16 + quad * 4;
            const float4 bv = *(const float4*)&b_in[bn * 256 + nl];
            ushort4 r4;
            r4.x = f2bf(acc[i][j][0] + bv.x);
            r4.y = f2bf(acc[i][j][1] + bv.y);
            r4.z = f2bf(acc[i][j][2] + bv.z);
            r4.w = f2bf(acc[i][j][3] + bv.w);
            *(ushort4*)&X[ml * XLD + nl] = r4;
        }
    }
    __syncthreads();

    // ---- epilogue part 2: chunk-local scan (prev = 0 at chunk start)
    const int chalf = tid >> 8;             // 0..1
    const int cidx  = tid & 255;            // 0..255
    const int g     = 2 * bm + chalf;       // global chunk 0..511
    const int d     = bn * 256 + cidx;      // 0..511
    const int h     = d >> 6;
    const float alpha = 1.0f / (1.0f + expf(-alpha_param[h]));
    const float c     = 1.0f - alpha;

    const ushort* Xr  = X + chalf * 64 * XLD + cidx;
    ushort* zrow = zout + ((size_t)(bm * 128 + chalf * 64)) * DIM + d;

    float z = 0.f, prev = 0.f;
    #pragma unroll 8
    for (int r = 0; r < CHUNK; ++r) {
        float xv = bf2f(Xr[r * XLD]);
        z = c * z + alpha * (xv - prev);
        prev = xv;
        zrow[(size_t)r * DIM] = f2bf(z);
    }
    Lfin[(size_t)g * 512 + d]       = z;     // L' tail
    XpT[(size_t)(g + 1) * 512 + d]  = prev;  // xp tail -> next chunk's xpt
}

// =====================================================================
// Carry chain:  G_k = c*Z_k - alpha*xpt_k ;  Z_{k+1} = L'_k + c^63 * G_k
// =====================================================================
__global__ void scan_fixg_kernel(const float* __restrict__ Lfin,
                                 const float* __restrict__ XpT,
                                 const float* __restrict__ alpha_param,
                                 const float* __restrict__ init_state,
                                 float* __restrict__ G)
{
    int ch = blockIdx.x * blockDim.x + threadIdx.x;   // 0..2047
    if (ch >= NCHAN) return;
    const int b = ch >> 9;
    const int d = ch & (DIM - 1);
    const int h = d >> 6;
    const float alpha = 1.0f / (1.0f + expf(-alpha_param[h]));
    const float c = 1.0f - alpha;
    const float c2 = c * c, c4 = c2 * c2, c8 = c4 * c4,
                c16 = c8 * c8, c32 = c16 * c16;
    const float c63 = c32 * c16 * c8 * c4 * c2 * c;
    const float sinit = init_state[d];

    float Z = sinit;
    const float* Lp = Lfin + (size_t)(b * NCHUNK) * 512 + d;
    const float* Xp = XpT  + (size_t)(b * NCHUNK) * 512 + d;
    float*       Gp = G    + (size_t)(b * NCHUNK) * 512 + d;

    constexpr int PF = 16;
    float Lr[PF], Xr[PF];
    #pragma unroll
    for (int j = 0; j < PF; ++j) {
        Lr[j] = Lp[(size_t)j * 512];
        Xr[j] = Xp[(size_t)j * 512];
    }
    for (int gr = 0; gr < NCHUNK / PF; ++gr) {        // 8 groups
        #pragma unroll
        for (int j = 0; j < PF; ++j) {
            const int kl = gr * PF + j;
            const float xpt = (kl == 0) ? sinit : Xr[j];
            const float Lc  = Lr[j];
            if (gr + 1 < NCHUNK / PF) {
                Lr[j] = Lp[(size_t)((gr + 1) * PF + j) * 512];
                Xr[j] = Xp[(size_t)((gr + 1) * PF + j) * 512];
            }
            const float Gv = c * Z - alpha * xpt;
            Gp[(size_t)kl * 512] = Gv;
            Z = Lc + c63 * Gv;
        }
    }
}

// =====================================================================
// GEMM2: out = z @ W_out^T + b_out ; carry correction fused in A-staging:
//   a[tau, d] += c_h^tau * G[g][d]   (g = row>>6, tau = row&63)
// Same 3-set / 2-iteration-cover schedule. Per-P1 vmem: z usx8 + 2 G
// float4 + 2 GLDS = 5 ops. Ladder: k=0 -> 2, k=1..13 -> 5, 14 -> 2, 15 -> 0.
// =====================================================================
__global__ __launch_bounds__(512, 4) void gemm2_kernel(
        const ushort* __restrict__ Az, const ushort* __restrict__ Bw,
        const float* __restrict__ bias, float* __restrict__ Cout,
        const float* __restrict__ G, const float* __restrict__ alpha_param)
{
    __shared__ __align__(16) char smem[73728];
    ushort* As0 = (ushort*)smem;                 // 3 bufs x 4096 ushorts
    ushort* Bs0 = (ushort*)(smem + 24576);       // 3 bufs x 8192 ushorts

    const int tid = threadIdx.x;
    int bm, bn; tile_decode(bm, bn);

    const int lane = tid & 63;
    const int wave = tid >> 6;
    const int wr = wave >> 2, wc = wave & 3;
    const int quad = lane >> 4, r16 = lane & 15;

    const int srow  = tid >> 2;
    const int ks    = tid & 3;
    const int rx    = (srow >> 1) & 3;
    const int skoff = ks * 8;
    const ushort* Ag16 = Az + (size_t)(bm * 128 + srow) * DIM + skoff;
    const ushort* Bg0  = Bw + (size_t)(bn * 256 + srow) * DIM + ((ks ^ rx) << 3);
    const ushort* Bg1  = Bg0 + (size_t)128 * DIM;
    const int aWrOff = srow * 32 + ((ks ^ rx) << 3);

    // per-thread fixed row -> fixed (g, tau); c_h^tau as named scalars
    const int m   = bm * 128 + srow;
    const float* Gc = G + (size_t)(m >> 6) * 512;
    const float t1 = (float)(m & (CHUNK - 1));
    float fc0,fc1,fc2,fc3,fc4,fc5,fc6,fc7;
    {
        float a, c;
        a = 1.f/(1.f+expf(-alpha_param[0])); c = 1.f - a; fc0 = exp2f(t1 * log2f(c));
        a = 1.f/(1.f+expf(-alpha_param[1])); c = 1.f - a; fc1 = exp2f(t1 * log2f(c));
        a = 1.f/(1.f+expf(-alpha_param[2])); c = 1.f - a; fc2 = exp2f(t1 * log2f(c));
        a = 1.f/(1.f+expf(-alpha_param[3])); c = 1.f - a; fc3 = exp2f(t1 * log2f(c));
        a = 1.f/(1.f+expf(-alpha_param[4])); c = 1.f - a; fc4 = exp2f(t1 * log2f(c));
        a = 1.f/(1.f+expf(-alpha_param[5])); c = 1.f - a; fc5 = exp2f(t1 * log2f(c));
        a = 1.f/(1.f+expf(-alpha_param[6])); c = 1.f - a; fc6 = exp2f(t1 * log2f(c));
        a = 1.f/(1.f+expf(-alpha_param[7])); c = 1.f - a; fc7 = exp2f(t1 * log2f(c));
    }
    auto selfac = [&](int hh) -> float {
        float f = fc0;
        f = (hh == 1) ? fc1 : f;
        f = (hh == 2) ? fc2 : f;
        f = (hh == 3) ? fc3 : f;
        f = (hh == 4) ? fc4 : f;
        f = (hh == 5) ? fc5 : f;
        f = (hh == 6) ? fc6 : f;
        f = (hh == 7) ? fc7 : f;
        return f;
    };
    auto fixpack = [&](usx8 av, float4 z0, float4 z1, float fac) {
        usx8 w;
        w[0] = f2bf(bf2f(av[0]) + fac * z0.x);
        w[1] = f2bf(bf2f(av[1]) + fac * z0.y);
        w[2] = f2bf(bf2f(av[2]) + fac * z0.z);
        w[3] = f2bf(bf2f(av[3]) + fac * z0.w);
        w[4] = f2bf(bf2f(av[4]) + fac * z1.x);
        w[5] = f2bf(bf2f(av[5]) + fac * z1.y);
        w[6] = f2bf(bf2f(av[6]) + fac * z1.z);
        w[7] = f2bf(bf2f(av[7]) + fac * z1.w);
        return w;
    };

    f32x4 acc[4][4];
    #pragma unroll
    for (int i = 0; i < 4; i++)
        #pragma unroll
        for (int j = 0; j < 4; j++)
            acc[i][j] = f32x4{0.f, 0.f, 0.f, 0.f};

    auto stageB = [&](int k0, int b) {
        GLDS(Bg0 + k0, &Bs0[b * 8192 + tid * 8]);
        GLDS(Bg1 + k0, &Bs0[b * 8192 + 4096 + tid * 8]);
    };

    // 3 A reg sets: {z usx8, G lo, G hi} for A(t), t%3 == set index
    usx8 av0, av1, av2; float4 g0l, g0h, g1l, g1h, g2l, g2h;

    // prologue: load sets 0,1,2; stage B(0),B(1); write fixed As[0]
    av0 = *(const usx8*)(Ag16);
    g0l = *(const float4*)&Gc[skoff];      g0h = *(const float4*)&Gc[skoff + 4];
    av1 = *(const usx8*)(Ag16 + 32);
    g1l = *(const float4*)&Gc[32 + skoff]; g1h = *(const float4*)&Gc[32 + skoff + 4];
    av2 = *(const usx8*)(Ag16 + 64);
    g2l = *(const float4*)&Gc[64 + skoff]; g2h = *(const float4*)&Gc[64 + skoff + 4];
    stageB(0, 0);
    stageB(32, 1);
    *(usx8*)&As0[aWrOff] = fixpack(av0, g0l, g0h, selfac(skoff >> 6));

    const int rxr = (r16 >> 1) & 3;

    #pragma unroll
    for (int k = 0; k < NITER; ++k) {
        const int cur = k % 3;
        const int stg = (k + 2) % 3;
        const int wnx = (k + 1) % 3;

        // P2: ds_write fixed As[k+1] from set (k+1)%3 (2-iter-old loads)
        if (k + 1 < NITER) {
            const float fac = selfac((((k + 1) * 32) + skoff) >> 6);
            usx8 w;
            if (wnx == 0)      w = fixpack(av0, g0l, g0h, fac);
            else if (wnx == 1) w = fixpack(av1, g1l, g1h, fac);
            else               w = fixpack(av2, g2l, g2h, fac);
            *(usx8*)&As0[wnx * 4096 + aWrOff] = w;
        }
        if (k == 0)       WAITV(2);
        else if (k <= 13) WAITV(5);
        else if (k == 14) WAITV(2);
        else              WAITV(0);
        WAITL0();
        BAR();

        // P1 (POST-BAR): load set k%3 with A(k+3); stage B(k+2)
        if (k + 3 < NITER) {
            const int ko = (k + 3) * 32;
            if (cur == 0) {
                av0 = *(const usx8*)(Ag16 + ko);
                g0l = *(const float4*)&Gc[ko + skoff]; g0h = *(const float4*)&Gc[ko + skoff + 4];
            } else if (cur == 1) {
                av1 = *(const usx8*)(Ag16 + ko);
                g1l = *(const float4*)&Gc[ko + skoff]; g1h = *(const float4*)&Gc[ko + skoff + 4];
            } else {
                av2 = *(const usx8*)(Ag16 + ko);
                g2l = *(const float4*)&Gc[ko + skoff]; g2h = *(const float4*)&Gc[ko + skoff + 4];
            }
        }
        SBAR();
        if (k + 2 < NITER) stageB((k + 2) * 32, stg);

        bf16x8 af[4], bfr[4];
        #pragma unroll
        for (int i = 0; i < 4; i++)
            af[i] = *(const bf16x8*)&As0[cur * 4096 + (wr * 64 + i * 16 + r16) * 32
                                         + ((quad ^ rxr) << 3)];
        #pragma unroll
        for (int j = 0; j < 4; j++)
            bfr[j] = *(const bf16x8*)&Bs0[cur * 8192 + (wc * 64 + j * 16 + r16) * 32
                                          + ((quad ^ rxr) << 3)];

        #pragma unroll
        for (int i = 0; i < 4; i++)
            #pragma unroll
            for (int j = 0; j < 4; j++)
                acc[i][j] = __builtin_amdgcn_mfma_f32_16x16x32_bf16(
                                bfr[j], af[i], acc[i][j], 0, 0, 0);  // swapped
    }

    // epilogue: m = lane&15 (per i-tile), n = quad*4 + reg
    #pragma unroll
    for (int i = 0; i < 4; i++) {
        const int mr = bm * 128 + wr * 64 + i * 16 + r16;
        #pragma unroll
        for (int j = 0; j < 4; j++) {
            const int n0 = bn * 256 + wc * 64 + j * 16 + quad * 4;
            const float4 bv = *(const float4*)&bias[n0];
            float4 v = make_float4(acc[i][j][0] + bv.x, acc[i][j][1] + bv.y,
                                   acc[i][j][2] + bv.z, acc[i][j][3] + bv.w);
            *(float4*)&Cout[(size_t)mr * DIM + n0] = v;
        }
    }
}

extern "C" void kernel_launch(void* const* d_in, const int* in_sizes, int n_in,
                              void* d_out, int out_size, void* d_ws, size_t ws_size,
                              hipStream_t stream) {
    const float* x           = (const float*)d_in[0];
    const float* W_in        = (const float*)d_in[1];
    const float* b_in        = (const float*)d_in[2];
    const float* W_out       = (const float*)d_in[3];
    const float* b_out       = (const float*)d_in[4];
    const float* init_state  = (const float*)d_in[5];
    const float* alpha_param = (const float*)d_in[6];
    float* out = (float*)d_out;

    // workspace layout
    ushort* z_bf    = (ushort*)d_ws;                       // 32 MB
    ushort* win_bf  = z_bf   + (size_t)MROWS * DIM;        // 0.5 MB
    ushort* wout_bf = win_bf + (size_t)DIM * DIM;          // 0.5 MB
    float*  Lfin    = (float*)(wout_bf + (size_t)DIM * DIM);        // [512][512]
    float*  XpT     = Lfin + (size_t)NGCHUNK * 512;                 // [513][512]
    float*  G       = XpT  + (size_t)(NGCHUNK + 1) * 512;           // [512][512]

    const int nw4 = (DIM * DIM) / 4;          // 65,536
    weights_to_bf16_kernel<<<(2 * nw4 + 255) / 256, 256, 0, stream>>>(
        W_in, W_out, win_bf, nw4);

    dim3 g1(2, MROWS / 128);                  // (2, 256) = 512 blocks
    gemm1_scan_kernel<<<g1, 512, 0, stream>>>(
        x, win_bf, b_in, alpha_param, z_bf, Lfin, XpT);

    scan_fixg_kernel<<<NCHAN / 256, 256, 0, stream>>>(
        Lfin, XpT, alpha_param, init_state, G);

    dim3 g2(2, MROWS / 128);                  // (2, 256)
    gemm2_kernel<<<g2, 512, 0, stream>>>(
        z_bf, wout_bf, b_out, out, G, alpha_param);
}